// Round 22
// baseline (197.489 us; speedup 1.0000x reference)
//
#include <hip/hip_runtime.h>
#include <hip/hip_bf16.h>

#define EMBED 256
#define HEADS 8
#define LEVELS 4
#define POINTS 4
#define HEAD_DIM 32

typedef __attribute__((ext_vector_type(4))) float f32x4;
typedef __attribute__((ext_vector_type(2))) float f32x2;
typedef __attribute__((ext_vector_type(8))) short bf16x8;

__device__ inline float bu2f(unsigned short u) {
    union { unsigned int i; float f; } t; t.i = ((unsigned int)u) << 16; return t.f;
}
__device__ inline unsigned short f2bu(float f) {
    __hip_bfloat16 h = __float2bfloat16(f);
    return *(unsigned short*)&h;
}
__device__ inline bf16x8 cvt8(const float4 a, const float4 b) {
    union { bf16x8 v; unsigned short s[8]; } u;
    u.s[0] = f2bu(a.x); u.s[1] = f2bu(a.y); u.s[2] = f2bu(a.z); u.s[3] = f2bu(a.w);
    u.s[4] = f2bu(b.x); u.s[5] = f2bu(b.y); u.s[6] = f2bu(b.z); u.s[7] = f2bu(b.w);
    return u.v;
}

// Bijective XCD swizzle (m204): consecutive logical ids land on the SAME XCD.
__device__ inline int xcd_swizzle(int bid, int nwg) {
    const int q = nwg >> 3, r = nwg & 7;
    const int xcd = bid & 7, idx = bid >> 3;
    return (xcd < r) ? xcd * (q + 1) + idx : r * (q + 1) + (xcd - r) * q + idx;
}

// All four weight transposes in ONE launch.
// PRE-SWIZZLED: element k of row r stored at k ^ ((r&7)<<3) (involution within
// each 64-elem k-tile). Direct-readers apply the same XOR on the global column.
__global__ __launch_bounds__(256)
void pack_weights(const float* __restrict__ Woff, const float* __restrict__ Wattw,
                  const float* __restrict__ Wval, const float* __restrict__ Wout,
                  unsigned short* __restrict__ bexOA,
                  unsigned short* __restrict__ bexVal,
                  unsigned short* __restrict__ bexOut) {
    const int idx = blockIdx.x * 256 + threadIdx.x;   // 896*256 total
    const int r = idx >> 8, k = idx & 255;
    const int kx = k ^ ((r & 7) << 3);                // swizzled element slot
    if (r < 256) {
        bexOA[(size_t)r * 256 + kx] = f2bu(Woff[(size_t)k * 256 + r]);
    } else if (r < 384) {
        bexOA[(size_t)r * 256 + kx] = f2bu(Wattw[(size_t)k * 128 + (r - 256)]);
    } else if (r < 640) {
        bexVal[(size_t)(r - 384) * 256 + kx] = f2bu(Wval[(size_t)k * 256 + (r - 384)]);
    } else {
        bexOut[(size_t)(r - 640) * 256 + kx] = f2bu(Wout[(size_t)k * 256 + (r - 640)]);
    }
}

// Fused QV GEMM, 64x64 tiles, BARRIER-FREE K-loop: each lane loads its MFMA
// fragments directly from global (A: fp32 + inline bf16 cvt; B: bf16x8 with
// the pre-swizzle XOR applied to the global column). No LDS staging -> no
// vmcnt(0) barrier drain per k-step; loads pipeline freely across the K loop.
// LDS used only for the coalesced epilogue. MFMA inputs/order bit-identical
// to the staged version.
// Logical blocks [0, 4*mbv): value GEMM -> head-planar bf16 val_bf.
// Logical blocks [4*mbv, +6*mbq): query GEMM (Nt=384) -> bf16 off_bf / attw_bf.
__global__ __launch_bounds__(256)
void gemm_qv_f32a(const float* __restrict__ Aval, const float* __restrict__ Aq,
                  const unsigned short* __restrict__ BtVal,
                  const unsigned short* __restrict__ BtOA,
                  const float* __restrict__ b_val,
                  const float* __restrict__ b_off,
                  const float* __restrict__ b_attw,
                  unsigned short* __restrict__ val_bf,
                  unsigned short* __restrict__ off_bf,
                  unsigned short* __restrict__ attw_bf,
                  int Mv, int Mq, int mbv, int Lv, int nwg) {
    __shared__ unsigned short ET[64 * 72];     // epilogue tile only (9 KB)

    int b = xcd_swizzle(blockIdx.x, nwg);
    const float* A; const unsigned short* Bt;
    int M, n0, r0, mode;
    if (b < 4 * mbv) {
        mode = 1; A = Aval; Bt = BtVal; M = Mv;
        n0 = (b & 3) * 64; r0 = (b >> 2) * 64;
    } else {
        b -= 4 * mbv;
        mode = 2; A = Aq; Bt = BtOA; M = Mq;
        n0 = (b % 6) * 64; r0 = (b / 6) * 64;
    }

    const int tid = threadIdx.x;
    const int lane = tid & 63, wv = tid >> 6;
    const int wm = wv >> 1, wn = wv & 1;
    const int lr = lane & 15, kh = lane >> 4;
    const int kc = kh * 8;                     // col offset within 32-chunk

    // per-lane row pointers
    const float* ar[2];
    const unsigned short* br[2];
    int bx[2];
    #pragma unroll
    for (int i = 0; i < 2; ++i) {
        int ra = r0 + wm * 32 + i * 16 + lr;
        ra = ra < M ? ra : M - 1;
        ar[i] = A + (size_t)ra * 256;
    }
    #pragma unroll
    for (int j = 0; j < 2; ++j) {
        const int rb = n0 + wn * 32 + j * 16 + lr;   // always < Nt (exact tiles)
        br[j] = Bt + (size_t)rb * 256;
        bx[j] = (rb & 7) << 3;
    }

    f32x4 acc[2][2] = {};

    // prefetch A fragments for k-step 0
    float4 aP[2][2][2];
    #pragma unroll
    for (int i = 0; i < 2; ++i)
        #pragma unroll
        for (int kk = 0; kk < 2; ++kk) {
            aP[i][kk][0] = *(const float4*)&ar[i][kk * 32 + kc];
            aP[i][kk][1] = *(const float4*)&ar[i][kk * 32 + kc + 4];
        }

    #pragma unroll
    for (int t = 0; t < 4; ++t) {
        const int k0 = t * 64;

        float4 aN[2][2][2];
        if (t < 3) {
            #pragma unroll
            for (int i = 0; i < 2; ++i)
                #pragma unroll
                for (int kk = 0; kk < 2; ++kk) {
                    aN[i][kk][0] = *(const float4*)&ar[i][k0 + 64 + kk * 32 + kc];
                    aN[i][kk][1] = *(const float4*)&ar[i][k0 + 64 + kk * 32 + kc + 4];
                }
        }

        #pragma unroll
        for (int kk = 0; kk < 2; ++kk) {
            bf16x8 af[2], bfr[2];
            #pragma unroll
            for (int i = 0; i < 2; ++i)
                af[i] = cvt8(aP[i][kk][0], aP[i][kk][1]);
            #pragma unroll
            for (int j = 0; j < 2; ++j)
                bfr[j] = *(const bf16x8*)&br[j][k0 + ((kk * 32 + kc) ^ bx[j])];
            #pragma unroll
            for (int i = 0; i < 2; ++i)
                #pragma unroll
                for (int j = 0; j < 2; ++j)
                    acc[i][j] = __builtin_amdgcn_mfma_f32_16x16x32_bf16(af[i], bfr[j], acc[i][j], 0, 0, 0);
        }

        if (t < 3) {
            #pragma unroll
            for (int i = 0; i < 2; ++i)
                #pragma unroll
                for (int kk = 0; kk < 2; ++kk) {
                    aP[i][kk][0] = aN[i][kk][0];
                    aP[i][kk][1] = aN[i][kk][1];
                }
        }
    }

    // ---- epilogue: pack (bf16, +bias) into padded LDS tile, coalesced stores ----
    #pragma unroll
    for (int j = 0; j < 2; ++j) {
        const int colL = wn * 32 + j * 16 + lr;
        const int col = n0 + colL;
        const bool is2 = (mode == 2) && (col >= 256);
        const float bj = (mode == 1) ? b_val[col] : (is2 ? b_attw[col - 256] : b_off[col]);
        #pragma unroll
        for (int i = 0; i < 2; ++i) {
            const int rowL = wm * 32 + i * 16 + kh * 4;
            #pragma unroll
            for (int rr = 0; rr < 4; ++rr)
                ET[(rowL + rr) * 72 + colL] = f2bu(acc[i][j][rr] + bj);
        }
    }
    __syncthreads();

    for (int s = tid; s < 512; s += 256) {
        const int rowL = s >> 3, chunk = s & 7;
        const int row = r0 + rowL;
        if (row >= M) continue;
        const uint4 v = *(const uint4*)&ET[rowL * 72 + chunk * 8];
        const int col = n0 + chunk * 8;
        if (mode == 1) {
            const int nIdx = row >= Lv;
            const int pix = row - nIdx * Lv;
            *(uint4*)&val_bf[((size_t)(nIdx * 8 + (col >> 5)) * Lv + pix) * 32 + (col & 31)] = v;
        } else {
            if (col >= 256) *(uint4*)&attw_bf[(size_t)row * 128 + (col - 256)] = v;
            else            *(uint4*)&off_bf[(size_t)row * 256 + col] = v;
        }
    }
}

// Output GEMM, 64x64 tiles, BARRIER-FREE K-loop: A (interm, pre-swizzled) and
// B (bexOut, pre-swizzled) fragments read directly from global with the XOR
// applied to the column. LDS only for the float4-coalesced epilogue.
__global__ __launch_bounds__(256)
void gemm_out_mfma(const unsigned short* __restrict__ A,
                   const unsigned short* __restrict__ Bt,
                   const float* __restrict__ bias,
                   float* __restrict__ C,
                   int M, int nwg) {
    __shared__ float FT[64 * 36];              // epilogue tile (9 KB)
    const int b = xcd_swizzle(blockIdx.x, nwg);
    const int n0 = (b & 3) * 64;
    const int r0 = (b >> 2) * 64;
    const int tid = threadIdx.x;
    const int lane = tid & 63, wv = tid >> 6;
    const int wm = wv >> 1, wn = wv & 1;
    const int lr = lane & 15, kh = lane >> 4;
    const int kc = kh * 8;

    const unsigned short* ar[2];
    const unsigned short* br[2];
    int ax[2], bx[2];
    #pragma unroll
    for (int i = 0; i < 2; ++i) {
        int ra = r0 + wm * 32 + i * 16 + lr;
        ra = ra < M ? ra : M - 1;
        ar[i] = A + (size_t)ra * 256;
        ax[i] = (ra & 7) << 3;
    }
    #pragma unroll
    for (int j = 0; j < 2; ++j) {
        const int rb = n0 + wn * 32 + j * 16 + lr;
        br[j] = Bt + (size_t)rb * 256;
        bx[j] = (rb & 7) << 3;
    }

    f32x4 acc[2][2] = {};

    #pragma unroll
    for (int t = 0; t < 4; ++t) {
        const int k0 = t * 64;
        #pragma unroll
        for (int kk = 0; kk < 2; ++kk) {
            bf16x8 af[2], bfr[2];
            #pragma unroll
            for (int i = 0; i < 2; ++i)
                af[i] = *(const bf16x8*)&ar[i][k0 + ((kk * 32 + kc) ^ ax[i])];
            #pragma unroll
            for (int j = 0; j < 2; ++j)
                bfr[j] = *(const bf16x8*)&br[j][k0 + ((kk * 32 + kc) ^ bx[j])];
            #pragma unroll
            for (int i = 0; i < 2; ++i)
                #pragma unroll
                for (int j = 0; j < 2; ++j)
                    acc[i][j] = __builtin_amdgcn_mfma_f32_16x16x32_bf16(af[i], bfr[j], acc[i][j], 0, 0, 0);
        }
    }

    // ---- epilogue: two passes (col halves, owned by wn), float4 stores ----
    #pragma unroll
    for (int p = 0; p < 2; ++p) {
        if (wn == p) {
            #pragma unroll
            for (int j = 0; j < 2; ++j) {
                const int colL = j * 16 + lr;
                const float bj = bias[n0 + p * 32 + colL];
                #pragma unroll
                for (int i = 0; i < 2; ++i) {
                    const int rowL = wm * 32 + i * 16 + kh * 4;
                    #pragma unroll
                    for (int rr = 0; rr < 4; ++rr)
                        FT[(rowL + rr) * 36 + colL] = acc[i][j][rr] + bj;
                }
            }
        }
        __syncthreads();
        for (int s = tid; s < 512; s += 256) {
            const int rowL = s >> 3, chunk = s & 7;
            const int row = r0 + rowL;
            if (row < M) {
                const float4 v = *(const float4*)&FT[rowL * 36 + chunk * 4];
                *(float4*)&C[(size_t)row * 256 + n0 + p * 32 + chunk * 4] = v;
            }
        }
        __syncthreads();
    }
}

// Sampling v14 (R20 known-good): head-planar block decomposition; each XCD owns
// 2 adjacent (n,h) planes -> L2-resident gathers. Writes interm PRE-SWIZZLED.
// val is head-planar: ((n*8+h)*Lv + pix)*32 + c.
// NOTE: corner reads are unconditional (weight 0 for invalid); val_bf needs
// ~1MB head guard and ~64KB tail guard in the workspace.
__global__ __launch_bounds__(256)
void msda_sample_v14(const unsigned short* __restrict__ off_bf,  // (NLq, 256) bf16
                     const unsigned short* __restrict__ attw_bf, // (NLq, 128) bf16
                     const float* __restrict__ refp,             // (NLq, LEVELS, 4)
                     const unsigned short* __restrict__ val,     // head-planar bf16
                     unsigned short* __restrict__ interm,        // (NLq, 256) bf16 out (pre-swizzled)
                     int Lq, int Lv, int nqb, int nwg) {
    __shared__ int    s_a[1024];
    __shared__ float4 s_w[1024];

    const int tid = threadIdx.x;
    const int lane = tid & 63;
    const int wv = tid >> 6;                 // wave 0..3
    const int wbase = wv * 256;              // private LDS region

    const int b = xcd_swizzle(blockIdx.x, nwg);
    const int plane = b / nqb;               // 0..15 = n*8 + h
    const int qchunk = b % nqb;
    const int n = plane >> 3, h = plane & 7;
    const int qbase = qchunk * 64 + wv * 16; // this wave's first query (within Lq)

    const int Hs[4]    = {100, 50, 25, 13};
    const int Ws[4]    = {152, 76, 38, 19};
    const int baseL[4] = {0, 15200, 19000, 19950};

    // ---- Phase 1: 256 (q,p) tasks per wave, 4 per lane ----
    {
        const int p = lane & 15;
        const int l = p >> 2;
        const int Wl = Ws[l], Hl = Hs[l];

        #pragma unroll
        for (int it = 0; it < 4; ++it) {
            const int t = it * 64 + lane;          // 0..255
            const int q = t >> 4;                  // 0..15
            const int qrow = qbase + q;
            const int e = wbase + q * 16 + ((p + 3 * (q & 7)) & 15);

            if (qrow >= Lq) {
                s_a[e] = 0;
                s_w[e] = make_float4(0.f, 0.f, 0.f, 0.f);
                continue;
            }
            const size_t grow = (size_t)n * Lq + qrow;

            const float lgt = bu2f(attw_bf[grow * 128 + h * 16 + p]);
            float mx = lgt;
            #pragma unroll
            for (int mask = 1; mask < 16; mask <<= 1)
                mx = fmaxf(mx, __shfl_xor(mx, mask));
            const float ex = __expf(lgt - mx);
            float sm = ex;
            #pragma unroll
            for (int mask = 1; mask < 16; mask <<= 1)
                sm += __shfl_xor(sm, mask);
            const float w_att = ex / sm;

            const unsigned int offu = *(const unsigned int*)&off_bf[grow * 256 + h * 32 + p * 2];
            const float ox = __uint_as_float(offu << 16);
            const float oy = __uint_as_float(offu & 0xFFFF0000u);
            const float4 rp4 = *(const float4*)&refp[(grow * 4 + l) * 4];

            const float ix = fmaf(ox, rp4.z * 0.125f, rp4.x) * (float)Wl - 0.5f;
            const float iy = fmaf(oy, rp4.w * 0.125f, rp4.y) * (float)Hl - 0.5f;
            const float x0f = floorf(ix), y0f = floorf(iy);
            const int x0 = (int)x0f, y0 = (int)y0f;
            const float wx1 = ix - x0f, wy1 = iy - y0f;
            const float wx0 = 1.f - wx1, wy0 = 1.f - wy1;

            const int a0 = (plane * Lv + baseL[l] + y0 * Wl + x0) * 32;

            const bool vx0 = (x0 >= 0) & (x0 < Wl);
            const bool vx1 = (x0 + 1 >= 0) & (x0 + 1 < Wl);
            const bool vy0 = (y0 >= 0) & (y0 < Hl);
            const bool vy1 = (y0 + 1 >= 0) & (y0 + 1 < Hl);

            float4 w;
            w.x = (vx0 && vy0) ? wx0 * wy0 * w_att : 0.f;
            w.y = (vx1 && vy0) ? wx1 * wy0 * w_att : 0.f;
            w.z = (vx0 && vy1) ? wx0 * wy1 * w_att : 0.f;
            w.w = (vx1 && vy1) ? wx1 * wy1 * w_att : 0.f;
            s_a[e] = a0;
            s_w[e] = w;
        }
    }

    // No __syncthreads: each wave reads only its own LDS region (lgkmcnt orders it).

    // ---- Phase 2: lane = (q, c8); 16 gathers batched per level ----
    const int q2 = lane >> 2;            // 0..15
    const int c8 = lane & 3;
    const int qrow2 = qbase + q2;
    const int ebase = wbase + q2 * 16;
    const int rot = 3 * (q2 & 7);
    const int coff = c8 * 8;

    f32x2 acc2[4] = {};

    #pragma unroll 1
    for (int l = 0; l < 4; ++l) {
        const int ystr = (l < 2 ? (l == 0 ? 152 : 76) : (l == 2 ? 38 : 19)) * 32;

        uint4 d[16];
        float4 ww[4];
        #pragma unroll
        for (int pp = 0; pp < 4; ++pp) {
            const int p = l * 4 + pp;
            const int e = ebase + ((p + rot) & 15);
            const int a0 = s_a[e] + coff;
            ww[pp] = s_w[e];
            d[pp * 4 + 0] = *(const uint4*)&val[a0];
            d[pp * 4 + 1] = *(const uint4*)&val[a0 + 32];
            d[pp * 4 + 2] = *(const uint4*)&val[a0 + ystr];
            d[pp * 4 + 3] = *(const uint4*)&val[a0 + ystr + 32];
        }

        // force all 16 loads (and the 4 LDS reads) to issue before any FMA
        __builtin_amdgcn_sched_barrier(0);

        #pragma unroll
        for (int pp = 0; pp < 4; ++pp) {
            const float wc[4] = {ww[pp].x, ww[pp].y, ww[pp].z, ww[pp].w};
            #pragma unroll
            for (int c = 0; c < 4; ++c) {
                const uint4 u = d[pp * 4 + c];
                const f32x2 wv2 = {wc[c], wc[c]};
                const unsigned int uu[4] = {u.x, u.y, u.z, u.w};
                #pragma unroll
                for (int i = 0; i < 4; ++i) {
                    f32x2 v;
                    v.x = __uint_as_float(uu[i] << 16);
                    v.y = __uint_as_float(uu[i] & 0xFFFF0000u);
                    acc2[i] = v * wv2 + acc2[i];
                }
            }
        }
    }

    if (qrow2 < Lq) {
        uint4 hiP;
        unsigned int* hp = (unsigned int*)&hiP;
        #pragma unroll
        for (int i = 0; i < 4; ++i) {
            hp[i] = (unsigned int)f2bu(acc2[i].x) | ((unsigned int)f2bu(acc2[i].y) << 16);
        }
        const size_t grow = (size_t)n * Lq + qrow2;
        const int kbase = (h * 32 + coff) ^ (((int)(grow & 7)) << 3);
        *(uint4*)&interm[grow * 256 + kbase] = hiP;
    }
}

extern "C" void kernel_launch(void* const* d_in, const int* in_sizes, int n_in,
                              void* d_out, int out_size, void* d_ws, size_t ws_size,
                              hipStream_t stream) {
    const float* query  = (const float*)d_in[0];
    const float* refp   = (const float*)d_in[1];
    const float* value  = (const float*)d_in[2];
    const float* W_off  = (const float*)d_in[4];
    const float* b_off  = (const float*)d_in[5];
    const float* W_attw = (const float*)d_in[6];
    const float* b_attw = (const float*)d_in[7];
    const float* W_val  = (const float*)d_in[8];
    const float* b_val  = (const float*)d_in[9];
    const float* W_out  = (const float*)d_in[10];
    const float* b_out  = (const float*)d_in[11];

    const int NLq = in_sizes[0] / EMBED;      // 40394
    const int NLv = in_sizes[2] / EMBED;      // 40404
    const int Lv = 15200 + 3800 + 950 + 247;  // 20197
    const int N = NLv / Lv;
    const int Lq = NLq / N;

    // Workspace layout: val_bf MUST NOT be first (sampling issues guarded-OOB
    // reads up to ~1MB before / ~400KB after it; weights give tail guard).
    unsigned short* attw_bf = (unsigned short*)d_ws;             // NLq*128 bf16
    unsigned short* off_bf  = attw_bf + (size_t)NLq * 128;       // NLq*256 bf16
    unsigned short* interm  = off_bf + (size_t)NLq * 256;        // NLq*256 bf16 (pre-swizzled)
    unsigned short* val_bf  = interm + (size_t)NLq * 256;        // NLv*256 bf16 head-planar
    unsigned short* bexOA   = val_bf + (size_t)NLv * 256;        // 384*256 (tail guard + weights)
    unsigned short* bexVal  = bexOA + 384 * 256;                 // 256*256
    unsigned short* bexOut  = bexVal + 256 * 256;                // 256*256

    const dim3 blk(256);
    const int mbq = (NLq + 63) / 64;          // 632
    const int mbv = (NLv + 63) / 64;          // 632
    const int nwgQV = 4 * mbv + 6 * mbq;
    const int nwgOut = 4 * mbq;
    const int nqb = (Lq + 63) / 64;           // 316
    const int nwgS = 16 * nqb;                // 5056 (divisible by 8)

    // weights (one launch, pre-swizzled)
    pack_weights<<<dim3(896), blk, 0, stream>>>(W_off, W_attw, W_val, W_out,
                                                bexOA, bexVal, bexOut);

    // fused value + query GEMMs (fp32 A, barrier-free), one dispatch
    gemm_qv_f32a<<<dim3(nwgQV), blk, 0, stream>>>(
        value, query, bexVal, bexOA, b_val, b_off, b_attw,
        val_bf, off_bf, attw_bf, NLv, NLq, mbv, Lv, nwgQV);

    // sampling (head-planar blocks; writes interm pre-swizzled)
    msda_sample_v14<<<dim3(nwgS), blk, 0, stream>>>(off_bf, attw_bf, refp, val_bf,
                                                    interm, Lq, Lv, nqb, nwgS);

    // output projection (barrier-free, fp32 out)
    gemm_out_mfma<<<dim3(nwgOut), blk, 0, stream>>>(interm, bexOut, b_out,
                                                    (float*)d_out, NLq, nwgOut);
}

// Round 23
// 124.197 us; speedup vs baseline: 1.5901x; 1.5901x over previous
//
#include <hip/hip_runtime.h>
#include <hip/hip_bf16.h>

#define EMBED 256
#define HEADS 8
#define LEVELS 4
#define POINTS 4
#define HEAD_DIM 32

typedef __attribute__((ext_vector_type(4))) float f32x4;
typedef __attribute__((ext_vector_type(2))) float f32x2;
typedef __attribute__((ext_vector_type(8))) short bf16x8;

__device__ inline float bu2f(unsigned short u) {
    union { unsigned int i; float f; } t; t.i = ((unsigned int)u) << 16; return t.f;
}
__device__ inline unsigned short f2bu(float f) {
    __hip_bfloat16 h = __float2bfloat16(f);
    return *(unsigned short*)&h;
}

// Bijective XCD swizzle (m204): consecutive logical ids land on the SAME XCD.
__device__ inline int xcd_swizzle(int bid, int nwg) {
    const int q = nwg >> 3, r = nwg & 7;
    const int xcd = bid & 7, idx = bid >> 3;
    return (xcd < r) ? xcd * (q + 1) + idx : r * (q + 1) + (xcd - r) * q + idx;
}

// All four weight transposes in ONE launch.
// PRE-SWIZZLED: element k of row r stored at k ^ ((r&7)<<3) (involution within
// each 64-elem k-tile). LDS staging stays linear; all readers apply the XOR.
__global__ __launch_bounds__(256)
void pack_weights(const float* __restrict__ Woff, const float* __restrict__ Wattw,
                  const float* __restrict__ Wval, const float* __restrict__ Wout,
                  unsigned short* __restrict__ bexOA,
                  unsigned short* __restrict__ bexVal,
                  unsigned short* __restrict__ bexOut) {
    const int idx = blockIdx.x * 256 + threadIdx.x;   // 896*256 total
    const int r = idx >> 8, k = idx & 255;
    const int kx = k ^ ((r & 7) << 3);                // swizzled element slot
    if (r < 256) {
        bexOA[(size_t)r * 256 + kx] = f2bu(Woff[(size_t)k * 256 + r]);
    } else if (r < 384) {
        bexOA[(size_t)r * 256 + kx] = f2bu(Wattw[(size_t)k * 128 + (r - 256)]);
    } else if (r < 640) {
        bexVal[(size_t)(r - 384) * 256 + kx] = f2bu(Wval[(size_t)k * 256 + (r - 384)]);
    } else {
        bexOut[(size_t)(r - 640) * 256 + kx] = f2bu(Wout[(size_t)k * 256 + (r - 640)]);
    }
}

// Fused QV GEMM, 64x64 tiles, T3-minimum pipeline: B double-buffered (2x8KB),
// A single-buffered (8KB) = 24KB LDS (occupancy cap 6 blocks/CU >= observed 5).
// Per k-step: issue B(t+1)+A-loads(t+1) BEFORE compute(t), so the barrier's
// vmcnt(0) drain lands after MFMA covered the latency. Same fragments, same
// accumulation order as R21 -> bit-identical output.
// Logical blocks [0, 4*mbv): value GEMM -> head-planar bf16 val_bf.
// Logical blocks [4*mbv, +6*mbq): query GEMM (Nt=384) -> bf16 off_bf / attw_bf.
__global__ __launch_bounds__(256)
void gemm_qv_f32a(const float* __restrict__ Aval, const float* __restrict__ Aq,
                  const unsigned short* __restrict__ BtVal,
                  const unsigned short* __restrict__ BtOA,
                  const float* __restrict__ b_val,
                  const float* __restrict__ b_off,
                  const float* __restrict__ b_attw,
                  unsigned short* __restrict__ val_bf,
                  unsigned short* __restrict__ off_bf,
                  unsigned short* __restrict__ attw_bf,
                  int Mv, int Mq, int mbv, int Lv, int nwg) {
    __shared__ unsigned short SH[12288];       // 24 KB: A (4096) | B dbuf (2x4096)
    unsigned short* AsU = SH;                  // 64*64
    unsigned short* BsU0 = SH + 4096;
    unsigned short* BsU1 = SH + 8192;

    int b = xcd_swizzle(blockIdx.x, nwg);
    const float* A; const unsigned short* Bt;
    int M, n0, r0, mode;
    if (b < 4 * mbv) {
        mode = 1; A = Aval; Bt = BtVal; M = Mv;
        n0 = (b & 3) * 64; r0 = (b >> 2) * 64;
    } else {
        b -= 4 * mbv;
        mode = 2; A = Aq; Bt = BtOA; M = Mq;
        n0 = (b % 6) * 64; r0 = (b / 6) * 64;
    }

    const int tid = threadIdx.x;
    const int lane = tid & 63, wv = tid >> 6;
    const int wm = wv >> 1, wn = wv & 1;
    const int lr = lane & 15, kh = lane >> 4;

    // A staging decode (constant per thread)
    const int stRow[4] = {
        (0 * 1024 + tid * 4) >> 6, (1 * 1024 + tid * 4) >> 6,
        (2 * 1024 + tid * 4) >> 6, (3 * 1024 + tid * 4) >> 6};
    const int stK = (tid * 4) & 63;

    // B stage rows (constant)
    const int bRow0 = n0 + (wv * 2 + 0) * 8 + (lane >> 3);
    const int bRow1 = n0 + (wv * 2 + 1) * 8 + (lane >> 3);
    const int bOff = (lane & 7) * 8;

    f32x4 acc[2][2] = {};
    float4 areg[4];

    // ---- prologue: stage k=0 (B -> buf0, A -> regs -> LDS) ----
    {
        __builtin_amdgcn_global_load_lds(
            (const __attribute__((address_space(1))) void*)(Bt + (size_t)bRow0 * 256 + bOff),
            (__attribute__((address_space(3))) void*)(BsU0 + (wv * 2 + 0) * 512), 16, 0, 0);
        __builtin_amdgcn_global_load_lds(
            (const __attribute__((address_space(1))) void*)(Bt + (size_t)bRow1 * 256 + bOff),
            (__attribute__((address_space(3))) void*)(BsU0 + (wv * 2 + 1) * 512), 16, 0, 0);
        #pragma unroll
        for (int r = 0; r < 4; ++r) {
            int grow = r0 + stRow[r];
            grow = grow < M ? grow : M - 1;
            const float4 v = *(const float4*)&A[(size_t)grow * 256 + stK];
            ushort4 u;
            u.x = f2bu(v.x); u.y = f2bu(v.y); u.z = f2bu(v.z); u.w = f2bu(v.w);
            *(ushort4*)&AsU[stRow[r] * 64 + (stK ^ ((stRow[r] & 7) << 3))] = u;
        }
    }
    __syncthreads();

    #pragma unroll
    for (int t = 0; t < 4; ++t) {
        const int k0 = t * 64;
        unsigned short* Bcur = (t & 1) ? BsU1 : BsU0;
        unsigned short* Bnxt = (t & 1) ? BsU0 : BsU1;

        // ---- issue next-tile loads BEFORE compute (latency hidden by MFMA) ----
        if (t < 3) {
            const int k1 = k0 + 64;
            __builtin_amdgcn_global_load_lds(
                (const __attribute__((address_space(1))) void*)(Bt + (size_t)bRow0 * 256 + k1 + bOff),
                (__attribute__((address_space(3))) void*)(Bnxt + (wv * 2 + 0) * 512), 16, 0, 0);
            __builtin_amdgcn_global_load_lds(
                (const __attribute__((address_space(1))) void*)(Bt + (size_t)bRow1 * 256 + k1 + bOff),
                (__attribute__((address_space(3))) void*)(Bnxt + (wv * 2 + 1) * 512), 16, 0, 0);
            #pragma unroll
            for (int r = 0; r < 4; ++r) {
                int grow = r0 + stRow[r];
                grow = grow < M ? grow : M - 1;
                areg[r] = *(const float4*)&A[(size_t)grow * 256 + k1 + stK];
            }
        }

        // ---- compute(t) ----
        #pragma unroll
        for (int kk = 0; kk < 2; ++kk) {
            bf16x8 af[2], bfr[2];
            #pragma unroll
            for (int i = 0; i < 2; ++i) {
                const int rowA = wm * 32 + i * 16 + lr;
                const int colx = (kk * 32 + kh * 8) ^ ((rowA & 7) << 3);
                af[i] = *(const bf16x8*)&AsU[rowA * 64 + colx];
            }
            #pragma unroll
            for (int j = 0; j < 2; ++j) {
                const int rowB = wn * 32 + j * 16 + lr;
                const int colx = (kk * 32 + kh * 8) ^ ((rowB & 7) << 3);
                bfr[j] = *(const bf16x8*)&Bcur[rowB * 64 + colx];
            }
            #pragma unroll
            for (int i = 0; i < 2; ++i)
                #pragma unroll
                for (int j = 0; j < 2; ++j)
                    acc[i][j] = __builtin_amdgcn_mfma_f32_16x16x32_bf16(af[i], bfr[j], acc[i][j], 0, 0, 0);
        }

        if (t < 3) {
            // drain (covered by the compute above); all waves done reading AsU
            __syncthreads();
            // write next A tile; next B tile already landed in Bnxt
            #pragma unroll
            for (int r = 0; r < 4; ++r) {
                ushort4 u;
                u.x = f2bu(areg[r].x); u.y = f2bu(areg[r].y);
                u.z = f2bu(areg[r].z); u.w = f2bu(areg[r].w);
                *(ushort4*)&AsU[stRow[r] * 64 + (stK ^ ((stRow[r] & 7) << 3))] = u;
            }
            __syncthreads();   // vmcnt already 0; lgkm-only wait
        }
    }

    // ---- epilogue: pack (bf16, +bias) into padded LDS tile, coalesced stores ----
    __syncthreads();
    unsigned short* ET = SH;                   // 64 x 72 = 4608
    #pragma unroll
    for (int j = 0; j < 2; ++j) {
        const int colL = wn * 32 + j * 16 + lr;
        const int col = n0 + colL;
        const bool is2 = (mode == 2) && (col >= 256);
        const float bj = (mode == 1) ? b_val[col] : (is2 ? b_attw[col - 256] : b_off[col]);
        #pragma unroll
        for (int i = 0; i < 2; ++i) {
            const int rowL = wm * 32 + i * 16 + kh * 4;
            #pragma unroll
            for (int rr = 0; rr < 4; ++rr)
                ET[(rowL + rr) * 72 + colL] = f2bu(acc[i][j][rr] + bj);
        }
    }
    __syncthreads();

    for (int s = tid; s < 512; s += 256) {
        const int rowL = s >> 3, chunk = s & 7;
        const int row = r0 + rowL;
        if (row >= M) continue;
        const uint4 v = *(const uint4*)&ET[rowL * 72 + chunk * 8];
        const int col = n0 + chunk * 8;
        if (mode == 1) {
            const int nIdx = row >= Lv;
            const int pix = row - nIdx * Lv;
            *(uint4*)&val_bf[((size_t)(nIdx * 8 + (col >> 5)) * Lv + pix) * 32 + (col & 31)] = v;
        } else {
            if (col >= 256) *(uint4*)&attw_bf[(size_t)row * 128 + (col - 256)] = v;
            else            *(uint4*)&off_bf[(size_t)row * 256 + col] = v;
        }
    }
}

// Output GEMM, 64x64 tiles, LDS-transposed epilogue (R21 known-good, unchanged).
__global__ __launch_bounds__(256)
void gemm_out_mfma(const unsigned short* __restrict__ A,
                   const unsigned short* __restrict__ Bt,
                   const float* __restrict__ bias,
                   float* __restrict__ C,
                   int M, int nwg) {
    __shared__ unsigned short SH[8192];        // 16 KB
    unsigned short* AsU = SH;
    unsigned short* BsU = SH + 4096;
    const int b = xcd_swizzle(blockIdx.x, nwg);
    const int n0 = (b & 3) * 64;
    const int r0 = (b >> 2) * 64;
    const int tid = threadIdx.x;
    const int lane = tid & 63, wv = tid >> 6;
    const int wm = wv >> 1, wn = wv & 1;
    const int lr = lane & 15, kh = lane >> 4;

    f32x4 acc[2][2] = {};

    for (int k0 = 0; k0 < 256; k0 += 64) {
        #pragma unroll
        for (int i = 0; i < 2; ++i) {
            const int c = wv * 2 + i;
            int row = r0 + c * 8 + (lane >> 3);
            row = row < M ? row : M - 1;
            const unsigned short* src = A + (size_t)row * 256 + k0 + (lane & 7) * 8;
            __builtin_amdgcn_global_load_lds(
                (const __attribute__((address_space(1))) void*)src,
                (__attribute__((address_space(3))) void*)(AsU + c * 512), 16, 0, 0);
            const int nrow = n0 + c * 8 + (lane >> 3);
            const unsigned short* srcb = Bt + (size_t)nrow * 256 + k0 + (lane & 7) * 8;
            __builtin_amdgcn_global_load_lds(
                (const __attribute__((address_space(1))) void*)srcb,
                (__attribute__((address_space(3))) void*)(BsU + c * 512), 16, 0, 0);
        }
        __syncthreads();

        #pragma unroll
        for (int kk = 0; kk < 2; ++kk) {
            bf16x8 af[2], bfr[2];
            #pragma unroll
            for (int i = 0; i < 2; ++i) {
                const int rowA = wm * 32 + i * 16 + lr;
                const int colx = (kk * 32 + kh * 8) ^ ((rowA & 7) << 3);
                af[i] = *(const bf16x8*)&AsU[rowA * 64 + colx];
            }
            #pragma unroll
            for (int j = 0; j < 2; ++j) {
                const int rowB = wn * 32 + j * 16 + lr;
                const int colx = (kk * 32 + kh * 8) ^ ((rowB & 7) << 3);
                bfr[j] = *(const bf16x8*)&BsU[rowB * 64 + colx];
            }
            #pragma unroll
            for (int i = 0; i < 2; ++i)
                #pragma unroll
                for (int j = 0; j < 2; ++j)
                    acc[i][j] = __builtin_amdgcn_mfma_f32_16x16x32_bf16(af[i], bfr[j], acc[i][j], 0, 0, 0);
        }
        __syncthreads();
    }

    // ---- epilogue: two passes (col halves, owned by wn), float4 stores ----
    float* FT = (float*)SH;
    #pragma unroll
    for (int p = 0; p < 2; ++p) {
        if (wn == p) {
            #pragma unroll
            for (int j = 0; j < 2; ++j) {
                const int colL = j * 16 + lr;
                const float bj = bias[n0 + p * 32 + colL];
                #pragma unroll
                for (int i = 0; i < 2; ++i) {
                    const int rowL = wm * 32 + i * 16 + kh * 4;
                    #pragma unroll
                    for (int rr = 0; rr < 4; ++rr)
                        FT[(rowL + rr) * 36 + colL] = acc[i][j][rr] + bj;
                }
            }
        }
        __syncthreads();
        for (int s = tid; s < 512; s += 256) {
            const int rowL = s >> 3, chunk = s & 7;
            const int row = r0 + rowL;
            if (row < M) {
                const float4 v = *(const float4*)&FT[rowL * 36 + chunk * 4];
                *(float4*)&C[(size_t)row * 256 + n0 + p * 32 + chunk * 4] = v;
            }
        }
        __syncthreads();
    }
}

// Sampling v14 (R20 known-good): head-planar block decomposition; each XCD owns
// 2 adjacent (n,h) planes -> L2-resident gathers. Writes interm PRE-SWIZZLED.
// val is head-planar: ((n*8+h)*Lv + pix)*32 + c.
// NOTE: corner reads are unconditional (weight 0 for invalid); val_bf needs
// ~1MB head guard and ~64KB tail guard in the workspace.
__global__ __launch_bounds__(256)
void msda_sample_v14(const unsigned short* __restrict__ off_bf,  // (NLq, 256) bf16
                     const unsigned short* __restrict__ attw_bf, // (NLq, 128) bf16
                     const float* __restrict__ refp,             // (NLq, LEVELS, 4)
                     const unsigned short* __restrict__ val,     // head-planar bf16
                     unsigned short* __restrict__ interm,        // (NLq, 256) bf16 out (pre-swizzled)
                     int Lq, int Lv, int nqb, int nwg) {
    __shared__ int    s_a[1024];
    __shared__ float4 s_w[1024];

    const int tid = threadIdx.x;
    const int lane = tid & 63;
    const int wv = tid >> 6;                 // wave 0..3
    const int wbase = wv * 256;              // private LDS region

    const int b = xcd_swizzle(blockIdx.x, nwg);
    const int plane = b / nqb;               // 0..15 = n*8 + h
    const int qchunk = b % nqb;
    const int n = plane >> 3, h = plane & 7;
    const int qbase = qchunk * 64 + wv * 16; // this wave's first query (within Lq)

    const int Hs[4]    = {100, 50, 25, 13};
    const int Ws[4]    = {152, 76, 38, 19};
    const int baseL[4] = {0, 15200, 19000, 19950};

    // ---- Phase 1: 256 (q,p) tasks per wave, 4 per lane ----
    {
        const int p = lane & 15;
        const int l = p >> 2;
        const int Wl = Ws[l], Hl = Hs[l];

        #pragma unroll
        for (int it = 0; it < 4; ++it) {
            const int t = it * 64 + lane;          // 0..255
            const int q = t >> 4;                  // 0..15
            const int qrow = qbase + q;
            const int e = wbase + q * 16 + ((p + 3 * (q & 7)) & 15);

            if (qrow >= Lq) {
                s_a[e] = 0;
                s_w[e] = make_float4(0.f, 0.f, 0.f, 0.f);
                continue;
            }
            const size_t grow = (size_t)n * Lq + qrow;

            const float lgt = bu2f(attw_bf[grow * 128 + h * 16 + p]);
            float mx = lgt;
            #pragma unroll
            for (int mask = 1; mask < 16; mask <<= 1)
                mx = fmaxf(mx, __shfl_xor(mx, mask));
            const float ex = __expf(lgt - mx);
            float sm = ex;
            #pragma unroll
            for (int mask = 1; mask < 16; mask <<= 1)
                sm += __shfl_xor(sm, mask);
            const float w_att = ex / sm;

            const unsigned int offu = *(const unsigned int*)&off_bf[grow * 256 + h * 32 + p * 2];
            const float ox = __uint_as_float(offu << 16);
            const float oy = __uint_as_float(offu & 0xFFFF0000u);
            const float4 rp4 = *(const float4*)&refp[(grow * 4 + l) * 4];

            const float ix = fmaf(ox, rp4.z * 0.125f, rp4.x) * (float)Wl - 0.5f;
            const float iy = fmaf(oy, rp4.w * 0.125f, rp4.y) * (float)Hl - 0.5f;
            const float x0f = floorf(ix), y0f = floorf(iy);
            const int x0 = (int)x0f, y0 = (int)y0f;
            const float wx1 = ix - x0f, wy1 = iy - y0f;
            const float wx0 = 1.f - wx1, wy0 = 1.f - wy1;

            const int a0 = (plane * Lv + baseL[l] + y0 * Wl + x0) * 32;

            const bool vx0 = (x0 >= 0) & (x0 < Wl);
            const bool vx1 = (x0 + 1 >= 0) & (x0 + 1 < Wl);
            const bool vy0 = (y0 >= 0) & (y0 < Hl);
            const bool vy1 = (y0 + 1 >= 0) & (y0 + 1 < Hl);

            float4 w;
            w.x = (vx0 && vy0) ? wx0 * wy0 * w_att : 0.f;
            w.y = (vx1 && vy0) ? wx1 * wy0 * w_att : 0.f;
            w.z = (vx0 && vy1) ? wx0 * wy1 * w_att : 0.f;
            w.w = (vx1 && vy1) ? wx1 * wy1 * w_att : 0.f;
            s_a[e] = a0;
            s_w[e] = w;
        }
    }

    // No __syncthreads: each wave reads only its own LDS region (lgkmcnt orders it).

    // ---- Phase 2: lane = (q, c8); 16 gathers batched per level ----
    const int q2 = lane >> 2;            // 0..15
    const int c8 = lane & 3;
    const int qrow2 = qbase + q2;
    const int ebase = wbase + q2 * 16;
    const int rot = 3 * (q2 & 7);
    const int coff = c8 * 8;

    f32x2 acc2[4] = {};

    #pragma unroll 1
    for (int l = 0; l < 4; ++l) {
        const int ystr = (l < 2 ? (l == 0 ? 152 : 76) : (l == 2 ? 38 : 19)) * 32;

        uint4 d[16];
        float4 ww[4];
        #pragma unroll
        for (int pp = 0; pp < 4; ++pp) {
            const int p = l * 4 + pp;
            const int e = ebase + ((p + rot) & 15);
            const int a0 = s_a[e] + coff;
            ww[pp] = s_w[e];
            d[pp * 4 + 0] = *(const uint4*)&val[a0];
            d[pp * 4 + 1] = *(const uint4*)&val[a0 + 32];
            d[pp * 4 + 2] = *(const uint4*)&val[a0 + ystr];
            d[pp * 4 + 3] = *(const uint4*)&val[a0 + ystr + 32];
        }

        // force all 16 loads (and the 4 LDS reads) to issue before any FMA
        __builtin_amdgcn_sched_barrier(0);

        #pragma unroll
        for (int pp = 0; pp < 4; ++pp) {
            const float wc[4] = {ww[pp].x, ww[pp].y, ww[pp].z, ww[pp].w};
            #pragma unroll
            for (int c = 0; c < 4; ++c) {
                const uint4 u = d[pp * 4 + c];
                const f32x2 wv2 = {wc[c], wc[c]};
                const unsigned int uu[4] = {u.x, u.y, u.z, u.w};
                #pragma unroll
                for (int i = 0; i < 4; ++i) {
                    f32x2 v;
                    v.x = __uint_as_float(uu[i] << 16);
                    v.y = __uint_as_float(uu[i] & 0xFFFF0000u);
                    acc2[i] = v * wv2 + acc2[i];
                }
            }
        }
    }

    if (qrow2 < Lq) {
        uint4 hiP;
        unsigned int* hp = (unsigned int*)&hiP;
        #pragma unroll
        for (int i = 0; i < 4; ++i) {
            hp[i] = (unsigned int)f2bu(acc2[i].x) | ((unsigned int)f2bu(acc2[i].y) << 16);
        }
        const size_t grow = (size_t)n * Lq + qrow2;
        const int kbase = (h * 32 + coff) ^ (((int)(grow & 7)) << 3);
        *(uint4*)&interm[grow * 256 + kbase] = hiP;
    }
}

extern "C" void kernel_launch(void* const* d_in, const int* in_sizes, int n_in,
                              void* d_out, int out_size, void* d_ws, size_t ws_size,
                              hipStream_t stream) {
    const float* query  = (const float*)d_in[0];
    const float* refp   = (const float*)d_in[1];
    const float* value  = (const float*)d_in[2];
    const float* W_off  = (const float*)d_in[4];
    const float* b_off  = (const float*)d_in[5];
    const float* W_attw = (const float*)d_in[6];
    const float* b_attw = (const float*)d_in[7];
    const float* W_val  = (const float*)d_in[8];
    const float* b_val  = (const float*)d_in[9];
    const float* W_out  = (const float*)d_in[10];
    const float* b_out  = (const float*)d_in[11];

    const int NLq = in_sizes[0] / EMBED;      // 40394
    const int NLv = in_sizes[2] / EMBED;      // 40404
    const int Lv = 15200 + 3800 + 950 + 247;  // 20197
    const int N = NLv / Lv;
    const int Lq = NLq / N;

    // Workspace layout: val_bf MUST NOT be first (sampling issues guarded-OOB
    // reads up to ~1MB before / ~400KB after it; weights give tail guard).
    unsigned short* attw_bf = (unsigned short*)d_ws;             // NLq*128 bf16
    unsigned short* off_bf  = attw_bf + (size_t)NLq * 128;       // NLq*256 bf16
    unsigned short* interm  = off_bf + (size_t)NLq * 256;        // NLq*256 bf16 (pre-swizzled)
    unsigned short* val_bf  = interm + (size_t)NLq * 256;        // NLv*256 bf16 head-planar
    unsigned short* bexOA   = val_bf + (size_t)NLv * 256;        // 384*256 (tail guard + weights)
    unsigned short* bexVal  = bexOA + 384 * 256;                 // 256*256
    unsigned short* bexOut  = bexVal + 256 * 256;                // 256*256

    const dim3 blk(256);
    const int mbq = (NLq + 63) / 64;          // 632
    const int mbv = (NLv + 63) / 64;          // 632
    const int nwgQV = 4 * mbv + 6 * mbq;
    const int nwgOut = 4 * mbq;
    const int nqb = (Lq + 63) / 64;           // 316
    const int nwgS = 16 * nqb;                // 5056 (divisible by 8)

    // weights (one launch, pre-swizzled)
    pack_weights<<<dim3(896), blk, 0, stream>>>(W_off, W_attw, W_val, W_out,
                                                bexOA, bexVal, bexOut);

    // fused value + query GEMMs (fp32 A, T3-minimum pipeline), one dispatch
    gemm_qv_f32a<<<dim3(nwgQV), blk, 0, stream>>>(
        value, query, bexVal, bexOA, b_val, b_off, b_attw,
        val_bf, off_bf, attw_bf, NLv, NLq, mbv, Lv, nwgQV);

    // sampling (head-planar blocks; writes interm pre-swizzled)
    msda_sample_v14<<<dim3(nwgS), blk, 0, stream>>>(off_bf, attw_bf, refp, val_bf,
                                                    interm, Lq, Lv, nqb, nwgS);

    // output projection (fp32 out)
    gemm_out_mfma<<<dim3(nwgOut), blk, 0, stream>>>(interm, bexOut, b_out,
                                                    (float*)d_out, NLq, nwgOut);
}